// Round 5
// baseline (697.239 us; speedup 1.0000x reference)
//
#include <hip/hip_runtime.h>
#include <math.h>

#define N_USERS 60000
#define N_ITEMS 30000
#define N_NODES 90000
#define DD 64
#define FF 192              // 3*DD
#define FH 96               // FF/2 (bf16 pairs per row)
#define KK_TOT 1408         // 768 + 512 + 128
#define E_UND 500000
#define E_DIR 1000000
#define SCAN_NBLK 88        // ceil(90000/1024)

typedef __attribute__((ext_vector_type(8))) __bf16 bf16x8;
typedef __attribute__((ext_vector_type(8))) unsigned short u16x8;
typedef __attribute__((ext_vector_type(4))) float f32x4;

__device__ __forceinline__ unsigned short f2bf(float f) {
    unsigned int u = __float_as_uint(f);
    unsigned int r = (u + 0x7FFFu + ((u >> 16) & 1u)) >> 16;   // RNE
    return (unsigned short)r;
}
__device__ __forceinline__ float bf_lo(unsigned int x) { return __uint_as_float(x << 16); }
__device__ __forceinline__ float bf_hi(unsigned int x) { return __uint_as_float(x & 0xFFFF0000u); }
__device__ __forceinline__ float bf2f(unsigned short x) {
    return __uint_as_float((unsigned int)x << 16);
}
__device__ __forceinline__ unsigned int pack2(float a, float b) {
    return ((unsigned int)f2bf(b) << 16) | (unsigned int)f2bf(a);
}

// ---------------- edge-layout probe: int32 vs int64 storage ----------------
__global__ void k_mode(const int* __restrict__ ei, int* __restrict__ mode) {
    __shared__ int any;
    if (threadIdx.x == 0) any = 0;
    __syncthreads();
    if (ei[2 * threadIdx.x + 1] != 0) atomicOr(&any, 1);
    __syncthreads();
    if (threadIdx.x == 0) mode[0] = (any == 0) ? 1 : 0;   // 1 => int64 layout
}

__device__ __forceinline__ void load_pair(const int* __restrict__ ei, int md, int u,
                                          int& a, int& b) {
    if (md) { a = ei[2 * u]; b = ei[2 * (E_UND + u)]; }
    else    { a = ei[u];     b = ei[E_UND + u]; }
}

// ---------------- degree count ----------------
__global__ void k_deg(const int* __restrict__ ei, const int* __restrict__ mode,
                      int* __restrict__ deg) {
    int i = blockIdx.x * 256 + threadIdx.x;
    if (i >= E_UND) return;
    int md = mode[0];
    int a, b;
    load_pair(ei, md, i, a, b);
    atomicAdd(&deg[a], 1);
    atomicAdd(&deg[b], 1);
}

// ---------------- exclusive scan (3 kernels) ----------------
__global__ __launch_bounds__(1024) void k_scan1(const int* __restrict__ deg,
                                                int* __restrict__ offs,
                                                int* __restrict__ bsum) {
    __shared__ int tmp[1024];
    int b = blockIdx.x, t = threadIdx.x;
    int i = b * 1024 + t;
    int v = (i < N_NODES) ? deg[i] : 0;
    tmp[t] = v;
    __syncthreads();
    for (int off = 1; off < 1024; off <<= 1) {
        int add = (t >= off) ? tmp[t - off] : 0;
        __syncthreads();
        tmp[t] += add;
        __syncthreads();
    }
    offs[i] = tmp[t] - v;              // exclusive within block
    if (t == 1023) bsum[b] = tmp[t];
}

__global__ void k_scan2(const int* __restrict__ bsum, int* __restrict__ bscan) {
    if (threadIdx.x == 0) {
        int run = 0;
        for (int b = 0; b < SCAN_NBLK; b++) { bscan[b] = run; run += bsum[b]; }
    }
}

__global__ void k_scan3(const int* __restrict__ deg, int* __restrict__ offs,
                        const int* __restrict__ bscan, int* __restrict__ cursor,
                        float* __restrict__ rsq) {
    int i = blockIdx.x * 256 + threadIdx.x;
    if (i >= N_NODES) return;
    int o = offs[i] + bscan[i >> 10];
    offs[i] = o;
    cursor[i] = o;
    int dg = deg[i];
    if (dg < 1) dg = 1;
    rsq[i] = rsqrtf((float)dg);
}

// ---------------- CSR fill (counting-sort scatter) ----------------
__global__ void k_fill(const int* __restrict__ ei, const int* __restrict__ mode,
                       int* __restrict__ cursor, const float* __restrict__ rsq,
                       int* __restrict__ edst, float* __restrict__ eval) {
    int i = blockIdx.x * 256 + threadIdx.x;
    if (i >= E_DIR) return;
    int md = mode[0];
    int u = (i < E_UND) ? i : i - E_UND;
    int a, b;
    load_pair(ei, md, u, a, b);
    int s, d;
    if (i < E_UND) { s = a; d = b; } else { s = b; d = a; }
    int slot = atomicAdd(&cursor[s], 1);
    edst[slot] = d;
    eval[slot] = rsq[s] * rsq[d];
}

// ---------------- user rows: transpose copy into S + bf16 Xb ----------------
__global__ void k_users(const float* __restrict__ ue, float* __restrict__ S,
                        unsigned short* __restrict__ Xbs) {
    int idx = blockIdx.x * 256 + threadIdx.x;
    if (idx >= N_USERS * FF) return;
    int n = idx / FF;
    int r = idx - n * FF;
    int b = r >> 6, d = r & 63;
    float v = ue[((size_t)b * N_USERS + n) * DD + d];
    S[idx] = v;
    Xbs[idx] = f2bf(v);
}

// ---------------- W transpose+concat+bf16: Wtb[n][k], n=b*64+d ----------------
__global__ void k_cvt_w(const float* __restrict__ Wt, const float* __restrict__ Wi,
                        const float* __restrict__ Wst, unsigned short* __restrict__ Wtb) {
    int idx = blockIdx.x * 256 + threadIdx.x;
    if (idx >= FF * KK_TOT) return;
    int n = idx / KK_TOT;
    int k = idx - n * KK_TOT;
    int b = n >> 6, d = n & 63;
    float v;
    if (k < 768)       v = Wt [((size_t)b * 768 + k) * 64 + d];
    else if (k < 1280) v = Wi [((size_t)b * 512 + (k - 768)) * 64 + d];
    else               v = Wst[((size_t)b * 128 + (k - 1280)) * 64 + d];
    Wtb[idx] = f2bf(v);
}

// ---------------- W1 transpose to bf16: W1T[n][k] = W1[k][n], 128x192 -------
__global__ void k_cvt_w1(const float* __restrict__ Wu1, const float* __restrict__ Wi1,
                         unsigned short* __restrict__ W1Tu,
                         unsigned short* __restrict__ W1Ti) {
    int idx = blockIdx.x * 256 + threadIdx.x;
    if (idx >= 128 * FF) return;
    int n = idx / FF;
    int k = idx - n * FF;
    W1Tu[idx] = f2bf(Wu1[(size_t)k * 128 + n]);
    W1Ti[idx] = f2bf(Wi1[(size_t)k * 128 + n]);
}

// ---------------- item feature GEMM: all 3 heads fused, A read ONCE --------
// M=30000 N=192 K=1408. Tile 128x192, BK=64. 4 waves; wave w: rows w*32..+32,
// all 192 cols (2 tm x 12 tn accumulators). Epilogue writes fp32 S + bf16 Xb.
#define BM 128
#define BK 64
#define LDK 72   // padded LDS pitch (elements)

__global__ __launch_bounds__(256) void k_item_gemm_mfma3(
    const float* __restrict__ xt, const float* __restrict__ xi, const float* __restrict__ xs,
    const unsigned short* __restrict__ Wtb,
    const float* __restrict__ bt, const float* __restrict__ bi, const float* __restrict__ bst,
    float* __restrict__ S, unsigned short* __restrict__ Xbs) {
    __shared__ unsigned short Ash[BM * LDK];     // 18.4 KB
    __shared__ unsigned short Bsh[FF * LDK];     // 27.6 KB
    const int tid  = threadIdx.x;
    const int wave = tid >> 6;
    const int lane = tid & 63;
    const int row0 = blockIdx.x * BM;

    f32x4 acc[2][12];
#pragma unroll
    for (int tm = 0; tm < 2; tm++)
#pragma unroll
        for (int tn = 0; tn < 12; tn++) acc[tm][tn] = (f32x4){0.f, 0.f, 0.f, 0.f};

    for (int k0 = 0; k0 < KK_TOT; k0 += BK) {
        // --- stage A: 128 rows x 64 k, fp32 -> bf16 (1024 chunks of 8) -----
#pragma unroll
        for (int i = 0; i < 4; i++) {
            int id = tid + i * 256;
            int r = id >> 3;
            int c = (id & 7) << 3;
            int gr = row0 + r;
            int gk = k0 + c;
            float4 v0 = make_float4(0.f, 0.f, 0.f, 0.f);
            float4 v1 = v0;
            if (gr < N_ITEMS) {
                const float* src;
                int kl;
                if (gk < 768)       { src = xt + (size_t)gr * 768; kl = gk; }
                else if (gk < 1280) { src = xi + (size_t)gr * 512; kl = gk - 768; }
                else                { src = xs + (size_t)gr * 128; kl = gk - 1280; }
                v0 = *(const float4*)(src + kl);
                v1 = *(const float4*)(src + kl + 4);
            }
            u16x8 pk;
            pk[0] = f2bf(v0.x); pk[1] = f2bf(v0.y); pk[2] = f2bf(v0.z); pk[3] = f2bf(v0.w);
            pk[4] = f2bf(v1.x); pk[5] = f2bf(v1.y); pk[6] = f2bf(v1.z); pk[7] = f2bf(v1.w);
            *(u16x8*)(&Ash[r * LDK + c]) = pk;
        }
        // --- stage B: 192 n-rows x 64 k (1536 chunks of 8) -----------------
#pragma unroll
        for (int i = 0; i < 6; i++) {
            int id = tid + i * 256;
            int r = id >> 3;
            int c = (id & 7) << 3;
            *(u16x8*)(&Bsh[r * LDK + c]) =
                *(const u16x8*)(&Wtb[(size_t)r * KK_TOT + k0 + c]);
        }
        __syncthreads();
        // --- MFMA: 2 kk x (2 tm x 12 tn) -----------------------------------
#pragma unroll
        for (int kk = 0; kk < BK; kk += 32) {
            bf16x8 af[2];
#pragma unroll
            for (int tm = 0; tm < 2; tm++)
                af[tm] = *(const bf16x8*)(&Ash[(wave * 32 + tm * 16 + (lane & 15)) * LDK +
                                               kk + (lane >> 4) * 8]);
#pragma unroll
            for (int tn = 0; tn < 12; tn++) {
                bf16x8 bfr = *(const bf16x8*)(&Bsh[(tn * 16 + (lane & 15)) * LDK +
                                                   kk + (lane >> 4) * 8]);
#pragma unroll
                for (int tm = 0; tm < 2; tm++)
                    acc[tm][tn] = __builtin_amdgcn_mfma_f32_16x16x32_bf16(
                        af[tm], bfr, acc[tm][tn], 0, 0, 0);
            }
        }
        __syncthreads();
    }

    // --- epilogue: C/D layout col=lane&15, row=quad*4+reg; S fp32 + Xb bf16 -
    const int col16 = lane & 15;
    const int quad  = lane >> 4;
#pragma unroll
    for (int tn = 0; tn < 12; tn++) {
        int n = tn * 16 + col16;            // 0..191
        int b = n >> 6, d = n & 63;
        float bias = bt[b * 64 + d] + bi[b * 64 + d] + bst[b * 64 + d];
#pragma unroll
        for (int tm = 0; tm < 2; tm++) {
#pragma unroll
            for (int r = 0; r < 4; r++) {
                int row = row0 + wave * 32 + tm * 16 + quad * 4 + r;
                if (row < N_ITEMS) {
                    size_t o = (size_t)(N_USERS + row) * FF + n;
                    float v = acc[tm][tn][r] + bias;
                    S[o] = v;
                    Xbs[o] = f2bf(v);
                }
            }
        }
    }
}

// ---------------- SPMM bf16 gather, 4-wide unroll, fused S accumulate ------
__global__ __launch_bounds__(192) void k_spmm_bf(const unsigned int* __restrict__ Xb,
                                                 unsigned int* __restrict__ Yb,
                                                 float* __restrict__ S,
                                                 const int* __restrict__ offs,
                                                 const int* __restrict__ deg,
                                                 const int* __restrict__ edst,
                                                 const float* __restrict__ eval) {
    int t = threadIdx.x;
    int half = (t >= FH) ? 1 : 0;
    int c = t - half * FH;
    int n = blockIdx.x * 2 + half;
    int start = offs[n];
    int dg = deg[n];
    const int* ed = edst + start;
    const float* ev = eval + start;
    float a0 = 0.f, a1 = 0.f;
    for (int j = 0; j < dg; j += 4) {
        int last = dg - 1;
        int j1 = (j + 1 < dg) ? j + 1 : last;
        int j2 = (j + 2 < dg) ? j + 2 : last;
        int j3 = (j + 3 < dg) ? j + 3 : last;
        int d0 = ed[j], d1 = ed[j1], d2 = ed[j2], d3 = ed[j3];
        float v0 = ev[j];
        float v1 = (j + 1 < dg) ? ev[j1] : 0.f;
        float v2 = (j + 2 < dg) ? ev[j2] : 0.f;
        float v3 = (j + 3 < dg) ? ev[j3] : 0.f;
        unsigned int x0 = Xb[(size_t)d0 * FH + c];
        unsigned int x1 = Xb[(size_t)d1 * FH + c];
        unsigned int x2 = Xb[(size_t)d2 * FH + c];
        unsigned int x3 = Xb[(size_t)d3 * FH + c];
        a0 = fmaf(v0, bf_lo(x0), a0); a1 = fmaf(v0, bf_hi(x0), a1);
        a0 = fmaf(v1, bf_lo(x1), a0); a1 = fmaf(v1, bf_hi(x1), a1);
        a0 = fmaf(v2, bf_lo(x2), a0); a1 = fmaf(v2, bf_hi(x2), a1);
        a0 = fmaf(v3, bf_lo(x3), a0); a1 = fmaf(v3, bf_hi(x3), a1);
    }
    size_t o = (size_t)n * FH + c;
    Yb[o] = pack2(a0, a1);
    float2* Sp = (float2*)(S + (size_t)n * FF);
    float2 s = Sp[c];
    s.x += a0; s.y += a1;
    Sp[c] = s;
}

// ---------------- attention: MFMA MLP + softmax + readout ------------------
#define LDA 200

__global__ __launch_bounds__(256) void k_attn_mfma(
    const float* __restrict__ S,
    const unsigned short* __restrict__ W1T,   // 128 x 192 bf16 (pre-transposed)
    const float* __restrict__ B1,             // 128
    const float* __restrict__ W2,             // 128 x 3
    const float* __restrict__ B2,             // 3
    float* __restrict__ out,
    int node_base, int n_rows) {
    __shared__ unsigned short Atile[64 * LDA];
    __shared__ float aws[64][4];
    const int tid  = threadIdx.x;
    const int wave = tid >> 6;
    const int lane = tid & 63;
    const int row0 = blockIdx.x * 64;
    const float inv3 = 1.f / 3.f;

#pragma unroll
    for (int i = 0; i < 6; i++) {
        int id = tid + i * 256;
        int r = id / 24;
        int c = (id - r * 24) * 8;
        u16x8 pk;
        if (row0 + r < n_rows) {
            const float* src = S + (size_t)(node_base + row0 + r) * FF + c;
            float4 v0 = *(const float4*)(src);
            float4 v1 = *(const float4*)(src + 4);
            pk[0] = f2bf(v0.x * inv3); pk[1] = f2bf(v0.y * inv3);
            pk[2] = f2bf(v0.z * inv3); pk[3] = f2bf(v0.w * inv3);
            pk[4] = f2bf(v1.x * inv3); pk[5] = f2bf(v1.y * inv3);
            pk[6] = f2bf(v1.z * inv3); pk[7] = f2bf(v1.w * inv3);
        } else {
            pk = (u16x8){0, 0, 0, 0, 0, 0, 0, 0};
        }
        *(u16x8*)(&Atile[r * LDA + c]) = pk;
    }
    __syncthreads();

    f32x4 acc[8];
#pragma unroll
    for (int tn = 0; tn < 8; tn++) acc[tn] = (f32x4){0.f, 0.f, 0.f, 0.f};
    const int l16 = lane & 15;
    const int quad = lane >> 4;
#pragma unroll
    for (int kk = 0; kk < FF; kk += 32) {
        bf16x8 af = *(const bf16x8*)(&Atile[(wave * 16 + l16) * LDA + kk + quad * 8]);
#pragma unroll
        for (int tn = 0; tn < 8; tn++) {
            bf16x8 bf = *(const bf16x8*)(&W1T[(size_t)(tn * 16 + l16) * FF + kk + quad * 8]);
            acc[tn] = __builtin_amdgcn_mfma_f32_16x16x32_bf16(af, bf, acc[tn], 0, 0, 0);
        }
    }

    float pl[4][3];
#pragma unroll
    for (int r = 0; r < 4; r++) { pl[r][0] = 0.f; pl[r][1] = 0.f; pl[r][2] = 0.f; }
#pragma unroll
    for (int tn = 0; tn < 8; tn++) {
        int col = tn * 16 + l16;
        float b1v = B1[col];
        float w0 = W2[col * 3 + 0], w1 = W2[col * 3 + 1], w2v = W2[col * 3 + 2];
#pragma unroll
        for (int r = 0; r < 4; r++) {
            float h = fmaxf(acc[tn][r] + b1v, 0.f);
            pl[r][0] = fmaf(h, w0, pl[r][0]);
            pl[r][1] = fmaf(h, w1, pl[r][1]);
            pl[r][2] = fmaf(h, w2v, pl[r][2]);
        }
    }
#pragma unroll
    for (int m = 1; m <= 8; m <<= 1) {
#pragma unroll
        for (int r = 0; r < 4; r++) {
            pl[r][0] += __shfl_xor(pl[r][0], m, 64);
            pl[r][1] += __shfl_xor(pl[r][1], m, 64);
            pl[r][2] += __shfl_xor(pl[r][2], m, 64);
        }
    }
    float b20 = B2[0], b21 = B2[1], b22 = B2[2];
    if (l16 == 0) {
#pragma unroll
        for (int r = 0; r < 4; r++) {
            float l0 = pl[r][0] + b20, l1 = pl[r][1] + b21, l2 = pl[r][2] + b22;
            float mx = fmaxf(l0, fmaxf(l1, l2));
            float e0 = __expf(l0 - mx), e1 = __expf(l1 - mx), e2 = __expf(l2 - mx);
            float inv = 1.f / (e0 + e1 + e2);
            int rr = wave * 16 + quad * 4 + r;
            aws[rr][0] = e0 * inv; aws[rr][1] = e1 * inv; aws[rr][2] = e2 * inv;
        }
    }
    __syncthreads();

#pragma unroll
    for (int i = 0; i < 16; i++) {
        int flat = tid + i * 256;
        int r = flat >> 6, d = flat & 63;
        if (row0 + r < n_rows) {
            float a0 = aws[r][0], a1 = aws[r][1], a2 = aws[r][2];
            const unsigned short* Ar = &Atile[r * LDA];
            float v = a0 * bf2f(Ar[d]) + a1 * bf2f(Ar[64 + d]) + a2 * bf2f(Ar[128 + d]);
            out[(size_t)(node_base + row0 + r) * DD + d] = v;
        }
    }
}

// ---------------- launch ----------------
extern "C" void kernel_launch(void* const* d_in, const int* in_sizes, int n_in,
                              void* d_out, int out_size, void* d_ws, size_t ws_size,
                              hipStream_t stream) {
    (void)in_sizes; (void)n_in; (void)out_size; (void)ws_size;
    const float* x_txt    = (const float*)d_in[0];
    const float* x_img    = (const float*)d_in[1];
    const float* x_struct = (const float*)d_in[2];
    const float* user_emb = (const float*)d_in[3];
    const float* W_txt    = (const float*)d_in[4];
    const float* b_txt    = (const float*)d_in[5];
    const float* W_img    = (const float*)d_in[6];
    const float* b_img    = (const float*)d_in[7];
    const float* W_st     = (const float*)d_in[8];
    const float* b_st     = (const float*)d_in[9];
    const float* Wu1      = (const float*)d_in[10];
    const float* bu1      = (const float*)d_in[11];
    const float* Wu2      = (const float*)d_in[12];
    const float* bu2      = (const float*)d_in[13];
    const float* Wi1      = (const float*)d_in[14];
    const float* bi1      = (const float*)d_in[15];
    const float* Wi2      = (const float*)d_in[16];
    const float* bi2      = (const float*)d_in[17];
    const int*   ei       = (const int*)d_in[18];
    float* out = (float*)d_out;

    char* base = (char*)d_ws;
    size_t off = 0;
    auto take = [&](size_t bytes) -> void* {
        void* p = base + off;
        off += (bytes + 255) & ~(size_t)255;
        return p;
    };
    float* S           = (float*)take((size_t)N_NODES * FF * 4);
    unsigned int* Xb0  = (unsigned int*)take((size_t)N_NODES * FH * 4);
    unsigned int* Yb   = (unsigned int*)take((size_t)N_NODES * FH * 4);
    int* deg    = (int*)take((size_t)N_NODES * 4);
    int* offs   = (int*)take((size_t)SCAN_NBLK * 1024 * 4);
    int* cursor = (int*)take((size_t)N_NODES * 4);
    int* bsum   = (int*)take((size_t)SCAN_NBLK * 4);
    int* bscan  = (int*)take((size_t)SCAN_NBLK * 4);
    float* rsq  = (float*)take((size_t)N_NODES * 4);
    int* edst   = (int*)take((size_t)E_DIR * 4);
    float* eval = (float*)take((size_t)E_DIR * 4);
    int* mode   = (int*)take(256);
    unsigned short* Wtb  = (unsigned short*)take((size_t)FF * KK_TOT * 2);
    unsigned short* W1Tu = (unsigned short*)take((size_t)128 * FF * 2);
    unsigned short* W1Ti = (unsigned short*)take((size_t)128 * FF * 2);

    hipMemsetAsync(deg, 0, (size_t)N_NODES * 4, stream);

    k_mode<<<1, 256, 0, stream>>>(ei, mode);
    k_deg<<<(E_UND + 255) / 256, 256, 0, stream>>>(ei, mode, deg);
    k_scan1<<<SCAN_NBLK, 1024, 0, stream>>>(deg, offs, bsum);
    k_scan2<<<1, 64, 0, stream>>>(bsum, bscan);
    k_scan3<<<(N_NODES + 255) / 256, 256, 0, stream>>>(deg, offs, bscan, cursor, rsq);
    k_fill<<<(E_DIR + 255) / 256, 256, 0, stream>>>(ei, mode, cursor, rsq, edst, eval);

    k_users<<<(N_USERS * FF + 255) / 256, 256, 0, stream>>>(user_emb, S,
                                                            (unsigned short*)Xb0);
    k_cvt_w<<<(FF * KK_TOT + 255) / 256, 256, 0, stream>>>(W_txt, W_img, W_st, Wtb);
    k_cvt_w1<<<(128 * FF + 255) / 256, 256, 0, stream>>>(Wu1, Wi1, W1Tu, W1Ti);
    k_item_gemm_mfma3<<<(N_ITEMS + BM - 1) / BM, 256, 0, stream>>>(
        x_txt, x_img, x_struct, Wtb, b_txt, b_img, b_st, S, (unsigned short*)Xb0);

    k_spmm_bf<<<N_NODES / 2, 192, 0, stream>>>(Xb0, Yb, S, offs, deg, edst, eval);
    k_spmm_bf<<<N_NODES / 2, 192, 0, stream>>>(Yb, Xb0, S, offs, deg, edst, eval);

    k_attn_mfma<<<(N_USERS + 63) / 64, 256, 0, stream>>>(
        S, W1Tu, bu1, Wu2, bu2, out, 0, N_USERS);
    k_attn_mfma<<<(N_ITEMS + 63) / 64, 256, 0, stream>>>(
        S, W1Ti, bi1, Wi2, bi2, out, N_USERS, N_ITEMS);
}

// Round 6
// 676.758 us; speedup vs baseline: 1.0303x; 1.0303x over previous
//
#include <hip/hip_runtime.h>
#include <math.h>

#define N_USERS 60000
#define N_ITEMS 30000
#define N_NODES 90000
#define DD 64
#define FF 192              // 3*DD
#define FH 96               // FF/2 (bf16 pairs per row)
#define KK_TOT 1408         // 768 + 512 + 128
#define E_UND 500000
#define E_DIR 1000000
#define SCAN_NBLK 88        // ceil(90000/1024)

typedef __attribute__((ext_vector_type(8))) __bf16 bf16x8;
typedef __attribute__((ext_vector_type(8))) unsigned short u16x8;
typedef __attribute__((ext_vector_type(4))) float f32x4;

__device__ __forceinline__ unsigned short f2bf(float f) {
    unsigned int u = __float_as_uint(f);
    unsigned int r = (u + 0x7FFFu + ((u >> 16) & 1u)) >> 16;   // RNE
    return (unsigned short)r;
}
__device__ __forceinline__ float bf_lo(unsigned int x) { return __uint_as_float(x << 16); }
__device__ __forceinline__ float bf_hi(unsigned int x) { return __uint_as_float(x & 0xFFFF0000u); }
__device__ __forceinline__ float bf2f(unsigned short x) {
    return __uint_as_float((unsigned int)x << 16);
}
__device__ __forceinline__ unsigned int pack2(float a, float b) {
    return ((unsigned int)f2bf(b) << 16) | (unsigned int)f2bf(a);
}

// ---------------- edge-layout probe: int32 vs int64 storage ----------------
__global__ void k_mode(const int* __restrict__ ei, int* __restrict__ mode) {
    __shared__ int any;
    if (threadIdx.x == 0) any = 0;
    __syncthreads();
    if (ei[2 * threadIdx.x + 1] != 0) atomicOr(&any, 1);
    __syncthreads();
    if (threadIdx.x == 0) mode[0] = (any == 0) ? 1 : 0;   // 1 => int64 layout
}

__device__ __forceinline__ void load_pair(const int* __restrict__ ei, int md, int u,
                                          int& a, int& b) {
    if (md) { a = ei[2 * u]; b = ei[2 * (E_UND + u)]; }
    else    { a = ei[u];     b = ei[E_UND + u]; }
}

// ---------------- degree count ----------------
__global__ void k_deg(const int* __restrict__ ei, const int* __restrict__ mode,
                      int* __restrict__ deg) {
    int i = blockIdx.x * 256 + threadIdx.x;
    if (i >= E_UND) return;
    int md = mode[0];
    int a, b;
    load_pair(ei, md, i, a, b);
    atomicAdd(&deg[a], 1);
    atomicAdd(&deg[b], 1);
}

// ---------------- exclusive scan (3 kernels) ----------------
__global__ __launch_bounds__(1024) void k_scan1(const int* __restrict__ deg,
                                                int* __restrict__ offs,
                                                int* __restrict__ bsum) {
    __shared__ int tmp[1024];
    int b = blockIdx.x, t = threadIdx.x;
    int i = b * 1024 + t;
    int v = (i < N_NODES) ? deg[i] : 0;
    tmp[t] = v;
    __syncthreads();
    for (int off = 1; off < 1024; off <<= 1) {
        int add = (t >= off) ? tmp[t - off] : 0;
        __syncthreads();
        tmp[t] += add;
        __syncthreads();
    }
    offs[i] = tmp[t] - v;              // exclusive within block
    if (t == 1023) bsum[b] = tmp[t];
}

__global__ void k_scan2(const int* __restrict__ bsum, int* __restrict__ bscan) {
    if (threadIdx.x == 0) {
        int run = 0;
        for (int b = 0; b < SCAN_NBLK; b++) { bscan[b] = run; run += bsum[b]; }
    }
}

__global__ void k_scan3(const int* __restrict__ deg, int* __restrict__ offs,
                        const int* __restrict__ bscan, int* __restrict__ cursor,
                        float* __restrict__ rsq) {
    int i = blockIdx.x * 256 + threadIdx.x;
    if (i >= N_NODES) return;
    int o = offs[i] + bscan[i >> 10];
    offs[i] = o;
    cursor[i] = o;
    int dg = deg[i];
    if (dg < 1) dg = 1;
    rsq[i] = rsqrtf((float)dg);
}

// ---------------- CSR fill (counting-sort scatter) ----------------
__global__ void k_fill(const int* __restrict__ ei, const int* __restrict__ mode,
                       int* __restrict__ cursor, const float* __restrict__ rsq,
                       int* __restrict__ edst, float* __restrict__ eval) {
    int i = blockIdx.x * 256 + threadIdx.x;
    if (i >= E_DIR) return;
    int md = mode[0];
    int u = (i < E_UND) ? i : i - E_UND;
    int a, b;
    load_pair(ei, md, u, a, b);
    int s, d;
    if (i < E_UND) { s = a; d = b; } else { s = b; d = a; }
    int slot = atomicAdd(&cursor[s], 1);
    edst[slot] = d;
    eval[slot] = rsq[s] * rsq[d];
}

// ---------------- user rows: transpose copy into S + bf16 Xb ----------------
__global__ void k_users(const float* __restrict__ ue, float* __restrict__ S,
                        unsigned short* __restrict__ Xbs) {
    int idx = blockIdx.x * 256 + threadIdx.x;
    if (idx >= N_USERS * FF) return;
    int n = idx / FF;
    int r = idx - n * FF;
    int b = r >> 6, d = r & 63;
    float v = ue[((size_t)b * N_USERS + n) * DD + d];
    S[idx] = v;
    Xbs[idx] = f2bf(v);
}

// ---------------- W transpose+concat+bf16: Wtb[n][k], n=b*64+d ----------------
__global__ void k_cvt_w(const float* __restrict__ Wt, const float* __restrict__ Wi,
                        const float* __restrict__ Wst, unsigned short* __restrict__ Wtb) {
    int idx = blockIdx.x * 256 + threadIdx.x;
    if (idx >= FF * KK_TOT) return;
    int n = idx / KK_TOT;
    int k = idx - n * KK_TOT;
    int b = n >> 6, d = n & 63;
    float v;
    if (k < 768)       v = Wt [((size_t)b * 768 + k) * 64 + d];
    else if (k < 1280) v = Wi [((size_t)b * 512 + (k - 768)) * 64 + d];
    else               v = Wst[((size_t)b * 128 + (k - 1280)) * 64 + d];
    Wtb[idx] = f2bf(v);
}

// ---------------- W1 transpose to bf16: W1T[n][k] = W1[k][n], 128x192 -------
__global__ void k_cvt_w1(const float* __restrict__ Wu1, const float* __restrict__ Wi1,
                         unsigned short* __restrict__ W1Tu,
                         unsigned short* __restrict__ W1Ti) {
    int idx = blockIdx.x * 256 + threadIdx.x;
    if (idx >= 128 * FF) return;
    int n = idx / FF;
    int k = idx - n * FF;
    W1Tu[idx] = f2bf(Wu1[(size_t)k * 128 + n]);
    W1Ti[idx] = f2bf(Wi1[(size_t)k * 128 + n]);
}

// ---------------- item feature GEMM: BM=64, N split in 2, paired dispatch --
// M=30000 N=192 K=1408. Grid = 469 row-tiles x 2 N-halves (bid = row*2+nh) so
// both consumers of an A-tile run back-to-back -> A hits L2/L3 on 2nd read.
// 4 waves; wave w: rows w*16..+16, 6 tn tiles (96 cols).
#define BM 64
#define BNH 96
#define BK 64
#define LDK 72   // padded LDS pitch (elements)

__global__ __launch_bounds__(256) void k_item_gemm_mfma3(
    const float* __restrict__ xt, const float* __restrict__ xi, const float* __restrict__ xs,
    const unsigned short* __restrict__ Wtb,
    const float* __restrict__ bt, const float* __restrict__ bi, const float* __restrict__ bst,
    float* __restrict__ S, unsigned short* __restrict__ Xbs) {
    __shared__ unsigned short Ash[BM * LDK];      // 9.2 KB
    __shared__ unsigned short Bsh[BNH * LDK];     // 13.8 KB
    const int tid  = threadIdx.x;
    const int wave = tid >> 6;
    const int lane = tid & 63;
    const int row0 = (blockIdx.x >> 1) * BM;
    const int n0   = (blockIdx.x & 1) * BNH;

    f32x4 acc[6];
#pragma unroll
    for (int tn = 0; tn < 6; tn++) acc[tn] = (f32x4){0.f, 0.f, 0.f, 0.f};

    const int l16  = lane & 15;
    const int quad = lane >> 4;

    for (int k0 = 0; k0 < KK_TOT; k0 += BK) {
        // --- stage A: 64 rows x 64 k, fp32 -> bf16 (512 chunks of 8) -------
#pragma unroll
        for (int i = 0; i < 2; i++) {
            int id = tid + i * 256;
            int r = id >> 3;
            int c = (id & 7) << 3;
            int gr = row0 + r;
            int gk = k0 + c;
            float4 v0 = make_float4(0.f, 0.f, 0.f, 0.f);
            float4 v1 = v0;
            if (gr < N_ITEMS) {
                const float* src;
                int kl;
                if (gk < 768)       { src = xt + (size_t)gr * 768; kl = gk; }
                else if (gk < 1280) { src = xi + (size_t)gr * 512; kl = gk - 768; }
                else                { src = xs + (size_t)gr * 128; kl = gk - 1280; }
                v0 = *(const float4*)(src + kl);
                v1 = *(const float4*)(src + kl + 4);
            }
            u16x8 pk;
            pk[0] = f2bf(v0.x); pk[1] = f2bf(v0.y); pk[2] = f2bf(v0.z); pk[3] = f2bf(v0.w);
            pk[4] = f2bf(v1.x); pk[5] = f2bf(v1.y); pk[6] = f2bf(v1.z); pk[7] = f2bf(v1.w);
            *(u16x8*)(&Ash[r * LDK + c]) = pk;
        }
        // --- stage B: 96 n-rows x 64 k (768 chunks of 8) -------------------
#pragma unroll
        for (int i = 0; i < 3; i++) {
            int id = tid + i * 256;
            int r = id >> 3;
            int c = (id & 7) << 3;
            *(u16x8*)(&Bsh[r * LDK + c]) =
                *(const u16x8*)(&Wtb[(size_t)(n0 + r) * KK_TOT + k0 + c]);
        }
        __syncthreads();
        // --- MFMA: 2 kk x 6 tn ---------------------------------------------
#pragma unroll
        for (int kk = 0; kk < BK; kk += 32) {
            bf16x8 af = *(const bf16x8*)(&Ash[(wave * 16 + l16) * LDK + kk + quad * 8]);
#pragma unroll
            for (int tn = 0; tn < 6; tn++) {
                bf16x8 bfr = *(const bf16x8*)(&Bsh[(tn * 16 + l16) * LDK + kk + quad * 8]);
                acc[tn] = __builtin_amdgcn_mfma_f32_16x16x32_bf16(af, bfr, acc[tn], 0, 0, 0);
            }
        }
        __syncthreads();
    }

    // --- epilogue: C/D layout col=lane&15, row=quad*4+reg; S fp32 + Xb bf16 -
#pragma unroll
    for (int tn = 0; tn < 6; tn++) {
        int n = n0 + tn * 16 + l16;         // 0..191
        int b = n >> 6, d = n & 63;
        float bias = bt[b * 64 + d] + bi[b * 64 + d] + bst[b * 64 + d];
#pragma unroll
        for (int r = 0; r < 4; r++) {
            int row = row0 + wave * 16 + quad * 4 + r;
            if (row < N_ITEMS) {
                size_t o = (size_t)(N_USERS + row) * FF + n;
                float v = acc[tn][r] + bias;
                S[o] = v;
                Xbs[o] = f2bf(v);
            }
        }
    }
}

// ---------------- SPMM bf16 gather, 4-wide unroll, fused S accumulate ------
__global__ __launch_bounds__(192) void k_spmm_bf(const unsigned int* __restrict__ Xb,
                                                 unsigned int* __restrict__ Yb,
                                                 float* __restrict__ S,
                                                 const int* __restrict__ offs,
                                                 const int* __restrict__ deg,
                                                 const int* __restrict__ edst,
                                                 const float* __restrict__ eval) {
    int t = threadIdx.x;
    int half = (t >= FH) ? 1 : 0;
    int c = t - half * FH;
    int n = blockIdx.x * 2 + half;
    int start = offs[n];
    int dg = deg[n];
    const int* ed = edst + start;
    const float* ev = eval + start;
    float a0 = 0.f, a1 = 0.f;
    for (int j = 0; j < dg; j += 4) {
        int last = dg - 1;
        int j1 = (j + 1 < dg) ? j + 1 : last;
        int j2 = (j + 2 < dg) ? j + 2 : last;
        int j3 = (j + 3 < dg) ? j + 3 : last;
        int d0 = ed[j], d1 = ed[j1], d2 = ed[j2], d3 = ed[j3];
        float v0 = ev[j];
        float v1 = (j + 1 < dg) ? ev[j1] : 0.f;
        float v2 = (j + 2 < dg) ? ev[j2] : 0.f;
        float v3 = (j + 3 < dg) ? ev[j3] : 0.f;
        unsigned int x0 = Xb[(size_t)d0 * FH + c];
        unsigned int x1 = Xb[(size_t)d1 * FH + c];
        unsigned int x2 = Xb[(size_t)d2 * FH + c];
        unsigned int x3 = Xb[(size_t)d3 * FH + c];
        a0 = fmaf(v0, bf_lo(x0), a0); a1 = fmaf(v0, bf_hi(x0), a1);
        a0 = fmaf(v1, bf_lo(x1), a0); a1 = fmaf(v1, bf_hi(x1), a1);
        a0 = fmaf(v2, bf_lo(x2), a0); a1 = fmaf(v2, bf_hi(x2), a1);
        a0 = fmaf(v3, bf_lo(x3), a0); a1 = fmaf(v3, bf_hi(x3), a1);
    }
    size_t o = (size_t)n * FH + c;
    Yb[o] = pack2(a0, a1);
    float2* Sp = (float2*)(S + (size_t)n * FF);
    float2 s = Sp[c];
    s.x += a0; s.y += a1;
    Sp[c] = s;
}

// ---------------- attention: MFMA MLP + softmax + readout ------------------
#define LDA 200

__global__ __launch_bounds__(256) void k_attn_mfma(
    const float* __restrict__ S,
    const unsigned short* __restrict__ W1T,   // 128 x 192 bf16 (pre-transposed)
    const float* __restrict__ B1,             // 128
    const float* __restrict__ W2,             // 128 x 3
    const float* __restrict__ B2,             // 3
    float* __restrict__ out,
    int node_base, int n_rows) {
    __shared__ unsigned short Atile[64 * LDA];
    __shared__ float aws[64][4];
    const int tid  = threadIdx.x;
    const int wave = tid >> 6;
    const int lane = tid & 63;
    const int row0 = blockIdx.x * 64;
    const float inv3 = 1.f / 3.f;

#pragma unroll
    for (int i = 0; i < 6; i++) {
        int id = tid + i * 256;
        int r = id / 24;
        int c = (id - r * 24) * 8;
        u16x8 pk;
        if (row0 + r < n_rows) {
            const float* src = S + (size_t)(node_base + row0 + r) * FF + c;
            float4 v0 = *(const float4*)(src);
            float4 v1 = *(const float4*)(src + 4);
            pk[0] = f2bf(v0.x * inv3); pk[1] = f2bf(v0.y * inv3);
            pk[2] = f2bf(v0.z * inv3); pk[3] = f2bf(v0.w * inv3);
            pk[4] = f2bf(v1.x * inv3); pk[5] = f2bf(v1.y * inv3);
            pk[6] = f2bf(v1.z * inv3); pk[7] = f2bf(v1.w * inv3);
        } else {
            pk = (u16x8){0, 0, 0, 0, 0, 0, 0, 0};
        }
        *(u16x8*)(&Atile[r * LDA + c]) = pk;
    }
    __syncthreads();

    f32x4 acc[8];
#pragma unroll
    for (int tn = 0; tn < 8; tn++) acc[tn] = (f32x4){0.f, 0.f, 0.f, 0.f};
    const int l16 = lane & 15;
    const int quad = lane >> 4;
#pragma unroll
    for (int kk = 0; kk < FF; kk += 32) {
        bf16x8 af = *(const bf16x8*)(&Atile[(wave * 16 + l16) * LDA + kk + quad * 8]);
#pragma unroll
        for (int tn = 0; tn < 8; tn++) {
            bf16x8 bf = *(const bf16x8*)(&W1T[(size_t)(tn * 16 + l16) * FF + kk + quad * 8]);
            acc[tn] = __builtin_amdgcn_mfma_f32_16x16x32_bf16(af, bf, acc[tn], 0, 0, 0);
        }
    }

    float pl[4][3];
#pragma unroll
    for (int r = 0; r < 4; r++) { pl[r][0] = 0.f; pl[r][1] = 0.f; pl[r][2] = 0.f; }
#pragma unroll
    for (int tn = 0; tn < 8; tn++) {
        int col = tn * 16 + l16;
        float b1v = B1[col];
        float w0 = W2[col * 3 + 0], w1 = W2[col * 3 + 1], w2v = W2[col * 3 + 2];
#pragma unroll
        for (int r = 0; r < 4; r++) {
            float h = fmaxf(acc[tn][r] + b1v, 0.f);
            pl[r][0] = fmaf(h, w0, pl[r][0]);
            pl[r][1] = fmaf(h, w1, pl[r][1]);
            pl[r][2] = fmaf(h, w2v, pl[r][2]);
        }
    }
#pragma unroll
    for (int m = 1; m <= 8; m <<= 1) {
#pragma unroll
        for (int r = 0; r < 4; r++) {
            pl[r][0] += __shfl_xor(pl[r][0], m, 64);
            pl[r][1] += __shfl_xor(pl[r][1], m, 64);
            pl[r][2] += __shfl_xor(pl[r][2], m, 64);
        }
    }
    float b20 = B2[0], b21 = B2[1], b22 = B2[2];
    if (l16 == 0) {
#pragma unroll
        for (int r = 0; r < 4; r++) {
            float l0 = pl[r][0] + b20, l1 = pl[r][1] + b21, l2 = pl[r][2] + b22;
            float mx = fmaxf(l0, fmaxf(l1, l2));
            float e0 = __expf(l0 - mx), e1 = __expf(l1 - mx), e2 = __expf(l2 - mx);
            float inv = 1.f / (e0 + e1 + e2);
            int rr = wave * 16 + quad * 4 + r;
            aws[rr][0] = e0 * inv; aws[rr][1] = e1 * inv; aws[rr][2] = e2 * inv;
        }
    }
    __syncthreads();

#pragma unroll
    for (int i = 0; i < 16; i++) {
        int flat = tid + i * 256;
        int r = flat >> 6, d = flat & 63;
        if (row0 + r < n_rows) {
            float a0 = aws[r][0], a1 = aws[r][1], a2 = aws[r][2];
            const unsigned short* Ar = &Atile[r * LDA];
            float v = a0 * bf2f(Ar[d]) + a1 * bf2f(Ar[64 + d]) + a2 * bf2f(Ar[128 + d]);
            out[(size_t)(node_base + row0 + r) * DD + d] = v;
        }
    }
}

// ---------------- launch ----------------
extern "C" void kernel_launch(void* const* d_in, const int* in_sizes, int n_in,
                              void* d_out, int out_size, void* d_ws, size_t ws_size,
                              hipStream_t stream) {
    (void)in_sizes; (void)n_in; (void)out_size; (void)ws_size;
    const float* x_txt    = (const float*)d_in[0];
    const float* x_img    = (const float*)d_in[1];
    const float* x_struct = (const float*)d_in[2];
    const float* user_emb = (const float*)d_in[3];
    const float* W_txt    = (const float*)d_in[4];
    const float* b_txt    = (const float*)d_in[5];
    const float* W_img    = (const float*)d_in[6];
    const float* b_img    = (const float*)d_in[7];
    const float* W_st     = (const float*)d_in[8];
    const float* b_st     = (const float*)d_in[9];
    const float* Wu1      = (const float*)d_in[10];
    const float* bu1      = (const float*)d_in[11];
    const float* Wu2      = (const float*)d_in[12];
    const float* bu2      = (const float*)d_in[13];
    const float* Wi1      = (const float*)d_in[14];
    const float* bi1      = (const float*)d_in[15];
    const float* Wi2      = (const float*)d_in[16];
    const float* bi2      = (const float*)d_in[17];
    const int*   ei       = (const int*)d_in[18];
    float* out = (float*)d_out;

    char* base = (char*)d_ws;
    size_t off = 0;
    auto take = [&](size_t bytes) -> void* {
        void* p = base + off;
        off += (bytes + 255) & ~(size_t)255;
        return p;
    };
    float* S           = (float*)take((size_t)N_NODES * FF * 4);
    unsigned int* Xb0  = (unsigned int*)take((size_t)N_NODES * FH * 4);
    unsigned int* Yb   = (unsigned int*)take((size_t)N_NODES * FH * 4);
    int* deg    = (int*)take((size_t)N_NODES * 4);
    int* offs   = (int*)take((size_t)SCAN_NBLK * 1024 * 4);
    int* cursor = (int*)take((size_t)N_NODES * 4);
    int* bsum   = (int*)take((size_t)SCAN_NBLK * 4);
    int* bscan  = (int*)take((size_t)SCAN_NBLK * 4);
    float* rsq  = (float*)take((size_t)N_NODES * 4);
    int* edst   = (int*)take((size_t)E_DIR * 4);
    float* eval = (float*)take((size_t)E_DIR * 4);
    int* mode   = (int*)take(256);
    unsigned short* Wtb  = (unsigned short*)take((size_t)FF * KK_TOT * 2);
    unsigned short* W1Tu = (unsigned short*)take((size_t)128 * FF * 2);
    unsigned short* W1Ti = (unsigned short*)take((size_t)128 * FF * 2);

    hipMemsetAsync(deg, 0, (size_t)N_NODES * 4, stream);

    k_mode<<<1, 256, 0, stream>>>(ei, mode);
    k_deg<<<(E_UND + 255) / 256, 256, 0, stream>>>(ei, mode, deg);
    k_scan1<<<SCAN_NBLK, 1024, 0, stream>>>(deg, offs, bsum);
    k_scan2<<<1, 64, 0, stream>>>(bsum, bscan);
    k_scan3<<<(N_NODES + 255) / 256, 256, 0, stream>>>(deg, offs, bscan, cursor, rsq);
    k_fill<<<(E_DIR + 255) / 256, 256, 0, stream>>>(ei, mode, cursor, rsq, edst, eval);

    k_users<<<(N_USERS * FF + 255) / 256, 256, 0, stream>>>(user_emb, S,
                                                            (unsigned short*)Xb0);
    k_cvt_w<<<(FF * KK_TOT + 255) / 256, 256, 0, stream>>>(W_txt, W_img, W_st, Wtb);
    k_cvt_w1<<<(128 * FF + 255) / 256, 256, 0, stream>>>(Wu1, Wi1, W1Tu, W1Ti);
    k_item_gemm_mfma3<<<((N_ITEMS + BM - 1) / BM) * 2, 256, 0, stream>>>(
        x_txt, x_img, x_struct, Wtb, b_txt, b_img, b_st, S, (unsigned short*)Xb0);

    k_spmm_bf<<<N_NODES / 2, 192, 0, stream>>>(Xb0, Yb, S, offs, deg, edst, eval);
    k_spmm_bf<<<N_NODES / 2, 192, 0, stream>>>(Yb, Xb0, S, offs, deg, edst, eval);

    k_attn_mfma<<<(N_USERS + 63) / 64, 256, 0, stream>>>(
        S, W1Tu, bu1, Wu2, bu2, out, 0, N_USERS);
    k_attn_mfma<<<(N_ITEMS + 63) / 64, 256, 0, stream>>>(
        S, W1Ti, bi1, Wi2, bi2, out, N_USERS, N_ITEMS);
}

// Round 7
// 625.784 us; speedup vs baseline: 1.1142x; 1.0815x over previous
//
#include <hip/hip_runtime.h>
#include <math.h>

#define N_USERS 60000
#define N_ITEMS 30000
#define N_NODES 90000
#define DD 64
#define FF 192              // 3*DD
#define FH 96               // FF/2 (bf16 pairs per row)
#define KK_TOT 1408         // 768 + 512 + 128
#define E_UND 500000
#define E_DIR 1000000
#define SCAN_NBLK 88        // ceil(90000/1024)

typedef __attribute__((ext_vector_type(8))) __bf16 bf16x8;
typedef __attribute__((ext_vector_type(8))) unsigned short u16x8;
typedef __attribute__((ext_vector_type(4))) float f32x4;

__device__ __forceinline__ unsigned short f2bf(float f) {
    unsigned int u = __float_as_uint(f);
    unsigned int r = (u + 0x7FFFu + ((u >> 16) & 1u)) >> 16;   // RNE
    return (unsigned short)r;
}
__device__ __forceinline__ float bf_lo(unsigned int x) { return __uint_as_float(x << 16); }
__device__ __forceinline__ float bf_hi(unsigned int x) { return __uint_as_float(x & 0xFFFF0000u); }
__device__ __forceinline__ float bf2f(unsigned short x) {
    return __uint_as_float((unsigned int)x << 16);
}
__device__ __forceinline__ unsigned int pack2(float a, float b) {
    return ((unsigned int)f2bf(b) << 16) | (unsigned int)f2bf(a);
}

// ---------------- edge-layout probe: int32 vs int64 storage ----------------
__global__ void k_mode(const int* __restrict__ ei, int* __restrict__ mode) {
    __shared__ int any;
    if (threadIdx.x == 0) any = 0;
    __syncthreads();
    if (ei[2 * threadIdx.x + 1] != 0) atomicOr(&any, 1);
    __syncthreads();
    if (threadIdx.x == 0) mode[0] = (any == 0) ? 1 : 0;   // 1 => int64 layout
}

__device__ __forceinline__ void load_pair(const int* __restrict__ ei, int md, int u,
                                          int& a, int& b) {
    if (md) { a = ei[2 * u]; b = ei[2 * (E_UND + u)]; }
    else    { a = ei[u];     b = ei[E_UND + u]; }
}

// ---------------- degree count ----------------
__global__ void k_deg(const int* __restrict__ ei, const int* __restrict__ mode,
                      int* __restrict__ deg) {
    int i = blockIdx.x * 256 + threadIdx.x;
    if (i >= E_UND) return;
    int md = mode[0];
    int a, b;
    load_pair(ei, md, i, a, b);
    atomicAdd(&deg[a], 1);
    atomicAdd(&deg[b], 1);
}

// ---------------- exclusive scan (3 kernels) ----------------
__global__ __launch_bounds__(1024) void k_scan1(const int* __restrict__ deg,
                                                int* __restrict__ offs,
                                                int* __restrict__ bsum) {
    __shared__ int tmp[1024];
    int b = blockIdx.x, t = threadIdx.x;
    int i = b * 1024 + t;
    int v = (i < N_NODES) ? deg[i] : 0;
    tmp[t] = v;
    __syncthreads();
    for (int off = 1; off < 1024; off <<= 1) {
        int add = (t >= off) ? tmp[t - off] : 0;
        __syncthreads();
        tmp[t] += add;
        __syncthreads();
    }
    offs[i] = tmp[t] - v;              // exclusive within block
    if (t == 1023) bsum[b] = tmp[t];
}

__global__ void k_scan2(const int* __restrict__ bsum, int* __restrict__ bscan) {
    if (threadIdx.x == 0) {
        int run = 0;
        for (int b = 0; b < SCAN_NBLK; b++) { bscan[b] = run; run += bsum[b]; }
    }
}

__global__ void k_scan3(const int* __restrict__ deg, int* __restrict__ offs,
                        const int* __restrict__ bscan, int* __restrict__ cursor,
                        float* __restrict__ rsq) {
    int i = blockIdx.x * 256 + threadIdx.x;
    if (i >= N_NODES) return;
    int o = offs[i] + bscan[i >> 10];
    offs[i] = o;
    cursor[i] = o;
    int dg = deg[i];
    if (dg < 1) dg = 1;
    rsq[i] = rsqrtf((float)dg);
}

// ---------------- CSR fill (counting-sort scatter) ----------------
__global__ void k_fill(const int* __restrict__ ei, const int* __restrict__ mode,
                       int* __restrict__ cursor, const float* __restrict__ rsq,
                       int* __restrict__ edst, float* __restrict__ eval) {
    int i = blockIdx.x * 256 + threadIdx.x;
    if (i >= E_DIR) return;
    int md = mode[0];
    int u = (i < E_UND) ? i : i - E_UND;
    int a, b;
    load_pair(ei, md, u, a, b);
    int s, d;
    if (i < E_UND) { s = a; d = b; } else { s = b; d = a; }
    int slot = atomicAdd(&cursor[s], 1);
    edst[slot] = d;
    eval[slot] = rsq[s] * rsq[d];
}

// ---------------- user rows: transpose copy into bf16 Xb ----------------
__global__ void k_users(const float* __restrict__ ue, unsigned short* __restrict__ Xbs) {
    int idx = blockIdx.x * 256 + threadIdx.x;
    if (idx >= N_USERS * FF) return;
    int n = idx / FF;
    int r = idx - n * FF;
    int b = r >> 6, d = r & 63;
    Xbs[idx] = f2bf(ue[((size_t)b * N_USERS + n) * DD + d]);
}

// ---------------- W transpose+concat+bf16: Wtb[n][k], n=b*64+d ----------------
__global__ void k_cvt_w(const float* __restrict__ Wt, const float* __restrict__ Wi,
                        const float* __restrict__ Wst, unsigned short* __restrict__ Wtb) {
    int idx = blockIdx.x * 256 + threadIdx.x;
    if (idx >= FF * KK_TOT) return;
    int n = idx / KK_TOT;
    int k = idx - n * KK_TOT;
    int b = n >> 6, d = n & 63;
    float v;
    if (k < 768)       v = Wt [((size_t)b * 768 + k) * 64 + d];
    else if (k < 1280) v = Wi [((size_t)b * 512 + (k - 768)) * 64 + d];
    else               v = Wst[((size_t)b * 128 + (k - 1280)) * 64 + d];
    Wtb[idx] = f2bf(v);
}

// ---------------- W1 transpose to bf16: W1T[n][k] = W1[k][n], 128x192 -------
__global__ void k_cvt_w1(const float* __restrict__ Wu1, const float* __restrict__ Wi1,
                         unsigned short* __restrict__ W1Tu,
                         unsigned short* __restrict__ W1Ti) {
    int idx = blockIdx.x * 256 + threadIdx.x;
    if (idx >= 128 * FF) return;
    int n = idx / FF;
    int k = idx - n * FF;
    W1Tu[idx] = f2bf(Wu1[(size_t)k * 128 + n]);
    W1Ti[idx] = f2bf(Wi1[(size_t)k * 128 + n]);
}

// ---------------- item feature GEMM: BM=64, N split in 2, paired dispatch --
#define BM 64
#define BNH 96
#define BK 64
#define LDK 72   // padded LDS pitch (elements)

__global__ __launch_bounds__(256) void k_item_gemm_mfma3(
    const float* __restrict__ xt, const float* __restrict__ xi, const float* __restrict__ xs,
    const unsigned short* __restrict__ Wtb,
    const float* __restrict__ bt, const float* __restrict__ bi, const float* __restrict__ bst,
    unsigned short* __restrict__ Xbs) {
    __shared__ unsigned short Ash[BM * LDK];      // 9.2 KB
    __shared__ unsigned short Bsh[BNH * LDK];     // 13.8 KB
    const int tid  = threadIdx.x;
    const int wave = tid >> 6;
    const int lane = tid & 63;
    const int row0 = (blockIdx.x >> 1) * BM;
    const int n0   = (blockIdx.x & 1) * BNH;

    f32x4 acc[6];
#pragma unroll
    for (int tn = 0; tn < 6; tn++) acc[tn] = (f32x4){0.f, 0.f, 0.f, 0.f};

    const int l16  = lane & 15;
    const int quad = lane >> 4;

    for (int k0 = 0; k0 < KK_TOT; k0 += BK) {
#pragma unroll
        for (int i = 0; i < 2; i++) {
            int id = tid + i * 256;
            int r = id >> 3;
            int c = (id & 7) << 3;
            int gr = row0 + r;
            int gk = k0 + c;
            float4 v0 = make_float4(0.f, 0.f, 0.f, 0.f);
            float4 v1 = v0;
            if (gr < N_ITEMS) {
                const float* src;
                int kl;
                if (gk < 768)       { src = xt + (size_t)gr * 768; kl = gk; }
                else if (gk < 1280) { src = xi + (size_t)gr * 512; kl = gk - 768; }
                else                { src = xs + (size_t)gr * 128; kl = gk - 1280; }
                v0 = *(const float4*)(src + kl);
                v1 = *(const float4*)(src + kl + 4);
            }
            u16x8 pk;
            pk[0] = f2bf(v0.x); pk[1] = f2bf(v0.y); pk[2] = f2bf(v0.z); pk[3] = f2bf(v0.w);
            pk[4] = f2bf(v1.x); pk[5] = f2bf(v1.y); pk[6] = f2bf(v1.z); pk[7] = f2bf(v1.w);
            *(u16x8*)(&Ash[r * LDK + c]) = pk;
        }
#pragma unroll
        for (int i = 0; i < 3; i++) {
            int id = tid + i * 256;
            int r = id >> 3;
            int c = (id & 7) << 3;
            *(u16x8*)(&Bsh[r * LDK + c]) =
                *(const u16x8*)(&Wtb[(size_t)(n0 + r) * KK_TOT + k0 + c]);
        }
        __syncthreads();
#pragma unroll
        for (int kk = 0; kk < BK; kk += 32) {
            bf16x8 af = *(const bf16x8*)(&Ash[(wave * 16 + l16) * LDK + kk + quad * 8]);
#pragma unroll
            for (int tn = 0; tn < 6; tn++) {
                bf16x8 bfr = *(const bf16x8*)(&Bsh[(tn * 16 + l16) * LDK + kk + quad * 8]);
                acc[tn] = __builtin_amdgcn_mfma_f32_16x16x32_bf16(af, bfr, acc[tn], 0, 0, 0);
            }
        }
        __syncthreads();
    }

#pragma unroll
    for (int tn = 0; tn < 6; tn++) {
        int n = n0 + tn * 16 + l16;         // 0..191
        int b = n >> 6, d = n & 63;
        float bias = bt[b * 64 + d] + bi[b * 64 + d] + bst[b * 64 + d];
#pragma unroll
        for (int r = 0; r < 4; r++) {
            int row = row0 + wave * 16 + quad * 4 + r;
            if (row < N_ITEMS) {
                Xbs[(size_t)(N_USERS + row) * FF + n] = f2bf(acc[tn][r] + bias);
            }
        }
    }
}

// ---------------- SPMM bf16 gather, 4-wide unroll ----------------
__global__ __launch_bounds__(192) void k_spmm_bf(const unsigned int* __restrict__ Xb,
                                                 unsigned int* __restrict__ Yb,
                                                 const int* __restrict__ offs,
                                                 const int* __restrict__ deg,
                                                 const int* __restrict__ edst,
                                                 const float* __restrict__ eval) {
    int t = threadIdx.x;
    int half = (t >= FH) ? 1 : 0;
    int c = t - half * FH;
    int n = blockIdx.x * 2 + half;
    int start = offs[n];
    int dg = deg[n];
    const int* ed = edst + start;
    const float* ev = eval + start;
    float a0 = 0.f, a1 = 0.f;
    for (int j = 0; j < dg; j += 4) {
        int last = dg - 1;
        int j1 = (j + 1 < dg) ? j + 1 : last;
        int j2 = (j + 2 < dg) ? j + 2 : last;
        int j3 = (j + 3 < dg) ? j + 3 : last;
        int d0 = ed[j], d1 = ed[j1], d2 = ed[j2], d3 = ed[j3];
        float v0 = ev[j];
        float v1 = (j + 1 < dg) ? ev[j1] : 0.f;
        float v2 = (j + 2 < dg) ? ev[j2] : 0.f;
        float v3 = (j + 3 < dg) ? ev[j3] : 0.f;
        unsigned int x0 = Xb[(size_t)d0 * FH + c];
        unsigned int x1 = Xb[(size_t)d1 * FH + c];
        unsigned int x2 = Xb[(size_t)d2 * FH + c];
        unsigned int x3 = Xb[(size_t)d3 * FH + c];
        a0 = fmaf(v0, bf_lo(x0), a0); a1 = fmaf(v0, bf_hi(x0), a1);
        a0 = fmaf(v1, bf_lo(x1), a0); a1 = fmaf(v1, bf_hi(x1), a1);
        a0 = fmaf(v2, bf_lo(x2), a0); a1 = fmaf(v2, bf_hi(x2), a1);
        a0 = fmaf(v3, bf_lo(x3), a0); a1 = fmaf(v3, bf_hi(x3), a1);
    }
    Yb[(size_t)n * FH + c] = pack2(a0, a1);
}

// ---------------- attention: sum 3 bf16 layers + MFMA MLP + readout --------
#define LDA 200

__global__ __launch_bounds__(256) void k_attn_mfma(
    const unsigned int* __restrict__ X0,      // layer-0 bf16 pairs
    const unsigned int* __restrict__ X1,      // layer-1
    const unsigned int* __restrict__ X2,      // layer-2
    const unsigned short* __restrict__ W1T,   // 128 x 192 bf16 (pre-transposed)
    const float* __restrict__ B1,             // 128
    const float* __restrict__ W2,             // 128 x 3
    const float* __restrict__ B2,             // 3
    float* __restrict__ out,
    int node_base, int n_rows) {
    __shared__ unsigned short Atile[64 * LDA];
    __shared__ float aws[64][4];
    const int tid  = threadIdx.x;
    const int wave = tid >> 6;
    const int lane = tid & 63;
    const int row0 = blockIdx.x * 64;
    const float inv3 = 1.f / 3.f;

    // stage A: 64 rows x 96 uint-pairs; sum three bf16 layers in fp32, /3
#pragma unroll
    for (int i = 0; i < 6; i++) {
        int id = tid + i * 256;            // 0..1535
        int r = id / 24;
        int q = id - r * 24;               // uint group: 4 uints = 8 bf16 cols
        u16x8 pk;
        if (row0 + r < n_rows) {
            size_t base = (size_t)(node_base + row0 + r) * FH + q * 4;
            uint4 a = *(const uint4*)(X0 + base);
            uint4 b = *(const uint4*)(X1 + base);
            uint4 c = *(const uint4*)(X2 + base);
            pk[0] = f2bf((bf_lo(a.x) + bf_lo(b.x) + bf_lo(c.x)) * inv3);
            pk[1] = f2bf((bf_hi(a.x) + bf_hi(b.x) + bf_hi(c.x)) * inv3);
            pk[2] = f2bf((bf_lo(a.y) + bf_lo(b.y) + bf_lo(c.y)) * inv3);
            pk[3] = f2bf((bf_hi(a.y) + bf_hi(b.y) + bf_hi(c.y)) * inv3);
            pk[4] = f2bf((bf_lo(a.z) + bf_lo(b.z) + bf_lo(c.z)) * inv3);
            pk[5] = f2bf((bf_hi(a.z) + bf_hi(b.z) + bf_hi(c.z)) * inv3);
            pk[6] = f2bf((bf_lo(a.w) + bf_lo(b.w) + bf_lo(c.w)) * inv3);
            pk[7] = f2bf((bf_hi(a.w) + bf_hi(b.w) + bf_hi(c.w)) * inv3);
        } else {
            pk = (u16x8){0, 0, 0, 0, 0, 0, 0, 0};
        }
        *(u16x8*)(&Atile[r * LDA + q * 8]) = pk;
    }
    __syncthreads();

    f32x4 acc[8];
#pragma unroll
    for (int tn = 0; tn < 8; tn++) acc[tn] = (f32x4){0.f, 0.f, 0.f, 0.f};
    const int l16 = lane & 15;
    const int quad = lane >> 4;
#pragma unroll
    for (int kk = 0; kk < FF; kk += 32) {
        bf16x8 af = *(const bf16x8*)(&Atile[(wave * 16 + l16) * LDA + kk + quad * 8]);
#pragma unroll
        for (int tn = 0; tn < 8; tn++) {
            bf16x8 bf = *(const bf16x8*)(&W1T[(size_t)(tn * 16 + l16) * FF + kk + quad * 8]);
            acc[tn] = __builtin_amdgcn_mfma_f32_16x16x32_bf16(af, bf, acc[tn], 0, 0, 0);
        }
    }

    float pl[4][3];
#pragma unroll
    for (int r = 0; r < 4; r++) { pl[r][0] = 0.f; pl[r][1] = 0.f; pl[r][2] = 0.f; }
#pragma unroll
    for (int tn = 0; tn < 8; tn++) {
        int col = tn * 16 + l16;
        float b1v = B1[col];
        float w0 = W2[col * 3 + 0], w1 = W2[col * 3 + 1], w2v = W2[col * 3 + 2];
#pragma unroll
        for (int r = 0; r < 4; r++) {
            float h = fmaxf(acc[tn][r] + b1v, 0.f);
            pl[r][0] = fmaf(h, w0, pl[r][0]);
            pl[r][1] = fmaf(h, w1, pl[r][1]);
            pl[r][2] = fmaf(h, w2v, pl[r][2]);
        }
    }
#pragma unroll
    for (int m = 1; m <= 8; m <<= 1) {
#pragma unroll
        for (int r = 0; r < 4; r++) {
            pl[r][0] += __shfl_xor(pl[r][0], m, 64);
            pl[r][1] += __shfl_xor(pl[r][1], m, 64);
            pl[r][2] += __shfl_xor(pl[r][2], m, 64);
        }
    }
    float b20 = B2[0], b21 = B2[1], b22 = B2[2];
    if (l16 == 0) {
#pragma unroll
        for (int r = 0; r < 4; r++) {
            float l0 = pl[r][0] + b20, l1 = pl[r][1] + b21, l2 = pl[r][2] + b22;
            float mx = fmaxf(l0, fmaxf(l1, l2));
            float e0 = __expf(l0 - mx), e1 = __expf(l1 - mx), e2 = __expf(l2 - mx);
            float inv = 1.f / (e0 + e1 + e2);
            int rr = wave * 16 + quad * 4 + r;
            aws[rr][0] = e0 * inv; aws[rr][1] = e1 * inv; aws[rr][2] = e2 * inv;
        }
    }
    __syncthreads();

#pragma unroll
    for (int i = 0; i < 16; i++) {
        int flat = tid + i * 256;
        int r = flat >> 6, d = flat & 63;
        if (row0 + r < n_rows) {
            float a0 = aws[r][0], a1 = aws[r][1], a2 = aws[r][2];
            const unsigned short* Ar = &Atile[r * LDA];
            float v = a0 * bf2f(Ar[d]) + a1 * bf2f(Ar[64 + d]) + a2 * bf2f(Ar[128 + d]);
            out[(size_t)(node_base + row0 + r) * DD + d] = v;
        }
    }
}

// ---------------- launch ----------------
extern "C" void kernel_launch(void* const* d_in, const int* in_sizes, int n_in,
                              void* d_out, int out_size, void* d_ws, size_t ws_size,
                              hipStream_t stream) {
    (void)in_sizes; (void)n_in; (void)out_size; (void)ws_size;
    const float* x_txt    = (const float*)d_in[0];
    const float* x_img    = (const float*)d_in[1];
    const float* x_struct = (const float*)d_in[2];
    const float* user_emb = (const float*)d_in[3];
    const float* W_txt    = (const float*)d_in[4];
    const float* b_txt    = (const float*)d_in[5];
    const float* W_img    = (const float*)d_in[6];
    const float* b_img    = (const float*)d_in[7];
    const float* W_st     = (const float*)d_in[8];
    const float* b_st     = (const float*)d_in[9];
    const float* Wu1      = (const float*)d_in[10];
    const float* bu1      = (const float*)d_in[11];
    const float* Wu2      = (const float*)d_in[12];
    const float* bu2      = (const float*)d_in[13];
    const float* Wi1      = (const float*)d_in[14];
    const float* bi1      = (const float*)d_in[15];
    const float* Wi2      = (const float*)d_in[16];
    const float* bi2      = (const float*)d_in[17];
    const int*   ei       = (const int*)d_in[18];
    float* out = (float*)d_out;

    char* base = (char*)d_ws;
    size_t off = 0;
    auto take = [&](size_t bytes) -> void* {
        void* p = base + off;
        off += (bytes + 255) & ~(size_t)255;
        return p;
    };
    unsigned int* Xb0  = (unsigned int*)take((size_t)N_NODES * FH * 4);
    unsigned int* Yb   = (unsigned int*)take((size_t)N_NODES * FH * 4);
    unsigned int* Zb   = (unsigned int*)take((size_t)N_NODES * FH * 4);
    int* deg    = (int*)take((size_t)N_NODES * 4);
    int* offs   = (int*)take((size_t)SCAN_NBLK * 1024 * 4);
    int* cursor = (int*)take((size_t)N_NODES * 4);
    int* bsum   = (int*)take((size_t)SCAN_NBLK * 4);
    int* bscan  = (int*)take((size_t)SCAN_NBLK * 4);
    float* rsq  = (float*)take((size_t)N_NODES * 4);
    int* edst   = (int*)take((size_t)E_DIR * 4);
    float* eval = (float*)take((size_t)E_DIR * 4);
    int* mode   = (int*)take(256);
    unsigned short* Wtb  = (unsigned short*)take((size_t)FF * KK_TOT * 2);
    unsigned short* W1Tu = (unsigned short*)take((size_t)128 * FF * 2);
    unsigned short* W1Ti = (unsigned short*)take((size_t)128 * FF * 2);

    hipMemsetAsync(deg, 0, (size_t)N_NODES * 4, stream);

    k_mode<<<1, 256, 0, stream>>>(ei, mode);
    k_deg<<<(E_UND + 255) / 256, 256, 0, stream>>>(ei, mode, deg);
    k_scan1<<<SCAN_NBLK, 1024, 0, stream>>>(deg, offs, bsum);
    k_scan2<<<1, 64, 0, stream>>>(bsum, bscan);
    k_scan3<<<(N_NODES + 255) / 256, 256, 0, stream>>>(deg, offs, bscan, cursor, rsq);
    k_fill<<<(E_DIR + 255) / 256, 256, 0, stream>>>(ei, mode, cursor, rsq, edst, eval);

    k_users<<<(N_USERS * FF + 255) / 256, 256, 0, stream>>>(user_emb,
                                                            (unsigned short*)Xb0);
    k_cvt_w<<<(FF * KK_TOT + 255) / 256, 256, 0, stream>>>(W_txt, W_img, W_st, Wtb);
    k_cvt_w1<<<(128 * FF + 255) / 256, 256, 0, stream>>>(Wu1, Wi1, W1Tu, W1Ti);
    k_item_gemm_mfma3<<<((N_ITEMS + BM - 1) / BM) * 2, 256, 0, stream>>>(
        x_txt, x_img, x_struct, Wtb, b_txt, b_img, b_st, (unsigned short*)Xb0);

    k_spmm_bf<<<N_NODES / 2, 192, 0, stream>>>(Xb0, Yb, offs, deg, edst, eval);
    k_spmm_bf<<<N_NODES / 2, 192, 0, stream>>>(Yb, Zb, offs, deg, edst, eval);

    k_attn_mfma<<<(N_USERS + 63) / 64, 256, 0, stream>>>(
        Xb0, Yb, Zb, W1Tu, bu1, Wu2, bu2, out, 0, N_USERS);
    k_attn_mfma<<<(N_ITEMS + 63) / 64, 256, 0, stream>>>(
        Xb0, Yb, Zb, W1Ti, bi1, Wi2, bi2, out, N_USERS, N_ITEMS);
}